// Round 1
// baseline (1073.376 us; speedup 1.0000x reference)
//
#include <hip/hip_runtime.h>

#define NU 100000
#define NI 50000
#define NE 1000000
#define D  64

// ---- degree count via int atomics ----
__global__ void k_degrees(const int* __restrict__ src, const int* __restrict__ dst,
                          int* __restrict__ deg_u, int* __restrict__ deg_i, int ne) {
    int e = blockIdx.x * blockDim.x + threadIdx.x;
    if (e < ne) {
        atomicAdd(&deg_u[src[e]], 1);
        atomicAdd(&deg_i[dst[e]], 1);
    }
}

// ---- inv_deg per reference: deg>0 ? 1/deg : 0 ----
__global__ void k_inv(const int* __restrict__ deg, float* __restrict__ inv, int n) {
    int v = blockIdx.x * blockDim.x + threadIdx.x;
    if (v < n) {
        int d = deg[v];
        inv[v] = (d > 0) ? (1.0f / (float)d) : 0.0f;
    }
}

// ---- one wave (64 lanes) per edge: coalesced 256B row gather + 64 atomics ----
__global__ void k_scatter(const float* __restrict__ feat, const int* __restrict__ sidx,
                          const int* __restrict__ didx, float* __restrict__ acc, int ne) {
    int gtid = blockIdx.x * blockDim.x + threadIdx.x;
    int wave = gtid >> 6;
    int lane = threadIdx.x & 63;
    int nw   = (gridDim.x * blockDim.x) >> 6;
    for (int e = wave; e < ne; e += nw) {
        int s = sidx[e];
        int t = didx[e];
        float v = feat[s * D + lane];
        atomicAdd(&acc[t * D + lane], v);
    }
}

// ---- out = acc*inv_deg[v] + self*sw[v]  (out may alias self: per-thread RAW only) ----
__global__ void k_finalize(const float* __restrict__ acc, const float* self,
                           const float* __restrict__ sw, const float* __restrict__ inv,
                           float* out, int n64) {
    int idx = blockIdx.x * blockDim.x + threadIdx.x;
    if (idx < n64) {
        int v = idx >> 6;
        out[idx] = acc[idx] * inv[v] + self[idx] * sw[v];
    }
}

extern "C" void kernel_launch(void* const* d_in, const int* in_sizes, int n_in,
                              void* d_out, int out_size, void* d_ws, size_t ws_size,
                              hipStream_t stream) {
    const float* user_emb = (const float*)d_in[0];   // NU x 64
    const float* item_emb = (const float*)d_in[1];   // NI x 64
    const float* u_sw     = (const float*)d_in[2];   // NU
    const float* i_sw     = (const float*)d_in[3];   // NI
    const int*   esrc     = (const int*)d_in[4];     // NE (user idx)
    const int*   edst     = (const int*)d_in[5];     // NE (item idx)

    float* out_u = (float*)d_out;          // NU*64
    float* out_i = out_u + NU * D;         // NI*64

    // workspace layout (39.6 MB total)
    float* u_acc = (float*)d_ws;           // NU*64 f32
    float* i_acc = u_acc + NU * D;         // NI*64 f32
    int*   deg_u = (int*)(i_acc + NI * D); // NU int
    int*   deg_i = deg_u + NU;             // NI int
    float* inv_u = (float*)(deg_i + NI);   // NU f32
    float* inv_i = inv_u + NU;             // NI f32

    size_t acc_bytes  = (size_t)(NU + NI) * D * sizeof(float);       // both acc buffers
    size_t zero_bytes = acc_bytes + (size_t)(NU + NI) * 2 * 4;       // + deg arrays (inv overwritten anyway)

    hipMemsetAsync(d_ws, 0, zero_bytes, stream);

    const int B = 256;
    const int SGRID = 8192;   // 32768 waves, ~30 edges/wave

    // degrees + inverse degrees
    k_degrees<<<(NE + B - 1) / B, B, 0, stream>>>(esrc, edst, deg_u, deg_i, NE);
    k_inv<<<(NU + B - 1) / B, B, 0, stream>>>(deg_u, inv_u, NU);
    k_inv<<<(NI + B - 1) / B, B, 0, stream>>>(deg_i, inv_i, NI);

    // ---- round 1 ----
    k_scatter<<<SGRID, B, 0, stream>>>(user_emb, esrc, edst, i_acc, NE);   // u0 -> items
    k_scatter<<<SGRID, B, 0, stream>>>(item_emb, edst, esrc, u_acc, NE);   // i0 -> users
    k_finalize<<<(NI * D + B - 1) / B, B, 0, stream>>>(i_acc, item_emb, i_sw, inv_i, out_i, NI * D);
    k_finalize<<<(NU * D + B - 1) / B, B, 0, stream>>>(u_acc, user_emb, u_sw, inv_u, out_u, NU * D);

    // ---- round 2 (reads round-1 results from d_out) ----
    hipMemsetAsync(d_ws, 0, acc_bytes, stream);
    k_scatter<<<SGRID, B, 0, stream>>>(out_u, esrc, edst, i_acc, NE);      // u1 -> items
    k_scatter<<<SGRID, B, 0, stream>>>(out_i, edst, esrc, u_acc, NE);      // i1 -> users
    // finalize u2 first (i2 finalize doesn't need u1); both are in-place-safe
    k_finalize<<<(NU * D + B - 1) / B, B, 0, stream>>>(u_acc, out_u, u_sw, inv_u, out_u, NU * D);
    k_finalize<<<(NI * D + B - 1) / B, B, 0, stream>>>(i_acc, out_i, i_sw, inv_i, out_i, NI * D);
}

// Round 2
// 557.494 us; speedup vs baseline: 1.9254x; 1.9254x over previous
//
#include <hip/hip_runtime.h>

#define NU 100000
#define NI 50000
#define NE 1000000
#define D  64

// ---- degree count via int atomics (cheap: 2M cache-resident int atomics) ----
__global__ void k_degrees(const int* __restrict__ src, const int* __restrict__ dst,
                          int* __restrict__ deg_u, int* __restrict__ deg_i, int ne) {
    int e = blockIdx.x * blockDim.x + threadIdx.x;
    if (e < ne) {
        atomicAdd(&deg_u[src[e]], 1);
        atomicAdd(&deg_i[dst[e]], 1);
    }
}

// ---- two-level exclusive scan: per-block scan + block sums ----
__global__ void k_scan_block(const int* __restrict__ in, int* __restrict__ out,
                             int* __restrict__ bsums, int n) {
    __shared__ int s[1024];
    int tid = threadIdx.x;
    int i = blockIdx.x * 1024 + tid;
    int v = (i < n) ? in[i] : 0;
    s[tid] = v;
    __syncthreads();
    for (int off = 1; off < 1024; off <<= 1) {
        int t = (tid >= off) ? s[tid - off] : 0;
        __syncthreads();
        s[tid] += t;
        __syncthreads();
    }
    if (i < n) out[i] = s[tid] - v;          // exclusive within block
    if (tid == 1023) bsums[blockIdx.x] = s[1023];  // block total
}

__global__ void k_scan_sums(int* __restrict__ bsums, int nb) {
    __shared__ int s[1024];
    int tid = threadIdx.x;
    int v = (tid < nb) ? bsums[tid] : 0;
    s[tid] = v;
    __syncthreads();
    for (int off = 1; off < 1024; off <<= 1) {
        int t = (tid >= off) ? s[tid - off] : 0;
        __syncthreads();
        s[tid] += t;
        __syncthreads();
    }
    if (tid < nb) bsums[tid] = s[tid] - v;   // exclusive scan of block totals
}

__global__ void k_add_off(int* __restrict__ rp, const int* __restrict__ bsums,
                          int n, int total) {
    int i = blockIdx.x * 1024 + threadIdx.x;
    if (i < n) rp[i] += bsums[blockIdx.x];
    if (i == 0) rp[n] = total;               // total degree == NE always
}

// ---- counting-sort fill: both CSRs in one pass (2M int atomics on cursors) ----
__global__ void k_fill(const int* __restrict__ src, const int* __restrict__ dst,
                       int* __restrict__ cur_u, int* __restrict__ cur_i,
                       int* __restrict__ col_u, int* __restrict__ col_i, int ne) {
    int e = blockIdx.x * blockDim.x + threadIdx.x;
    if (e < ne) {
        int u = src[e], v = dst[e];
        col_u[atomicAdd(&cur_u[u], 1)] = v;  // user's list of item neighbors
        col_i[atomicAdd(&cur_i[v], 1)] = u;  // item's list of user neighbors
    }
}

// ---- pull aggregation + fused finalize: one wave per dst node, lane = dim ----
// out = mean(feat[neighbors]) + self*sw ; out may alias self (per-thread RAW only)
__global__ void k_agg(const float* __restrict__ feat, const float* self,
                      const float* __restrict__ sw, const int* __restrict__ rp,
                      const int* __restrict__ cols, float* out, int n_dst) {
    int gtid = blockIdx.x * blockDim.x + threadIdx.x;
    int w = gtid >> 6;
    int lane = threadIdx.x & 63;
    if (w >= n_dst) return;
    int beg = rp[w], end = rp[w + 1];
    float a0 = 0.f, a1 = 0.f, a2 = 0.f, a3 = 0.f;
    int j = beg;
    for (; j + 4 <= end; j += 4) {          // 4-wide unroll: 4 independent gathers in flight
        int c0 = cols[j], c1 = cols[j + 1], c2 = cols[j + 2], c3 = cols[j + 3];
        a0 += feat[c0 * D + lane];
        a1 += feat[c1 * D + lane];
        a2 += feat[c2 * D + lane];
        a3 += feat[c3 * D + lane];
    }
    for (; j < end; ++j) a0 += feat[cols[j] * D + lane];
    float acc = (a0 + a1) + (a2 + a3);
    int dgr = end - beg;
    float inv = (dgr > 0) ? (1.0f / (float)dgr) : 0.0f;
    out[w * D + lane] = acc * inv + self[w * D + lane] * sw[w];
}

extern "C" void kernel_launch(void* const* d_in, const int* in_sizes, int n_in,
                              void* d_out, int out_size, void* d_ws, size_t ws_size,
                              hipStream_t stream) {
    const float* user_emb = (const float*)d_in[0];   // NU x 64
    const float* item_emb = (const float*)d_in[1];   // NI x 64
    const float* u_sw     = (const float*)d_in[2];   // NU
    const float* i_sw     = (const float*)d_in[3];   // NI
    const int*   esrc     = (const int*)d_in[4];     // NE (user idx)
    const int*   edst     = (const int*)d_in[5];     // NE (item idx)

    float* out_u = (float*)d_out;          // NU*64
    float* out_i = out_u + NU * D;         // NI*64

    // workspace layout (~22.6 MB)
    int* deg_u = (int*)d_ws;               // NU
    int* deg_i = deg_u + NU;               // NI
    int* rp_u  = deg_i + NI;               // NU+1
    int* rp_i  = rp_u + NU + 1;            // NI+1
    int* cur_u = rp_i + NI + 1;            // NU
    int* cur_i = cur_u + NU;               // NI
    int* bsums = cur_i + NI;               // 1024
    int* col_u = bsums + 1024;             // NE
    int* col_i = col_u + NE;               // NE
    float* tmp_i = (float*)(col_i + NE);   // NI*64 f32 (round-1 item result)

    hipMemsetAsync(deg_u, 0, (size_t)(NU + NI) * sizeof(int), stream);

    const int B = 256;

    // degrees
    k_degrees<<<(NE + B - 1) / B, B, 0, stream>>>(esrc, edst, deg_u, deg_i, NE);

    // exclusive scans -> row pointers
    int nb_u = (NU + 1023) / 1024;  // 98
    int nb_i = (NI + 1023) / 1024;  // 49
    k_scan_block<<<nb_u, 1024, 0, stream>>>(deg_u, rp_u, bsums, NU);
    k_scan_sums<<<1, 1024, 0, stream>>>(bsums, nb_u);
    k_add_off<<<nb_u, 1024, 0, stream>>>(rp_u, bsums, NU, NE);
    k_scan_block<<<nb_i, 1024, 0, stream>>>(deg_i, rp_i, bsums, NI);
    k_scan_sums<<<1, 1024, 0, stream>>>(bsums, nb_i);
    k_add_off<<<nb_i, 1024, 0, stream>>>(rp_i, bsums, NI, NE);

    // cursors start at row offsets
    hipMemcpyAsync(cur_u, rp_u, (size_t)NU * sizeof(int), hipMemcpyDeviceToDevice, stream);
    hipMemcpyAsync(cur_i, rp_i, (size_t)NI * sizeof(int), hipMemcpyDeviceToDevice, stream);

    // CSR fill
    k_fill<<<(NE + B - 1) / B, B, 0, stream>>>(esrc, edst, cur_u, cur_i, col_u, col_i, NE);

    // wave-per-node grids: ceil(n/4) blocks of 256 (4 waves)
    int gi = (NI + 3) / 4;
    int gu = (NU + 3) / 4;

    // ---- round 1 ----
    // i1 = mean(u0) + i0*i_sw   -> tmp_i
    k_agg<<<gi, B, 0, stream>>>(user_emb, item_emb, i_sw, rp_i, col_i, tmp_i, NI);
    // u1 = mean(i0) + u0*u_sw   -> out_u
    k_agg<<<gu, B, 0, stream>>>(item_emb, user_emb, u_sw, rp_u, col_u, out_u, NU);

    // ---- round 2 ----
    // i2 = mean(u1) + i1*i_sw   -> out_i   (reads out_u = u1, tmp_i = i1)
    k_agg<<<gi, B, 0, stream>>>(out_u, tmp_i, i_sw, rp_i, col_i, out_i, NI);
    // u2 = mean(i1) + u1*u_sw   -> out_u   (reads tmp_i = i1, self = out_u = u1, in-place)
    k_agg<<<gu, B, 0, stream>>>(tmp_i, out_u, u_sw, rp_u, col_u, out_u, NU);
}

// Round 3
// 368.547 us; speedup vs baseline: 2.9125x; 1.5127x over previous
//
#include <hip/hip_runtime.h>

#define NU 100000
#define NI 50000
#define NE 1000000
#define D  64
#define NBI 196            // item buckets, 256 items each  (50000 -> 196)
#define NBU 391            // user buckets, 256 users each  (100000 -> 391)
#define NB_TOT (NBI + NBU)
#define CHUNK 4096         // edges per k_part block (16 per thread)

// ---- bucket histograms for both partitions in one pass ----
__global__ void k_bhist(const int* __restrict__ esrc, const int* __restrict__ edst,
                        int* __restrict__ bcnt, int ne) {
    __shared__ int h[NB_TOT];
    for (int b = threadIdx.x; b < NB_TOT; b += blockDim.x) h[b] = 0;
    __syncthreads();
    int stride = gridDim.x * blockDim.x;
    for (int e = blockIdx.x * blockDim.x + threadIdx.x; e < ne; e += stride) {
        atomicAdd(&h[edst[e] >> 8], 1);          // item bucket
        atomicAdd(&h[NBI + (esrc[e] >> 8)], 1);  // user bucket
    }
    __syncthreads();
    for (int b = threadIdx.x; b < NB_TOT; b += blockDim.x) {
        int v = h[b];
        if (v) atomicAdd(&bcnt[b], v);
    }
}

// ---- tiny exclusive scan of bucket counts -> bucket bases + partition cursors ----
__global__ void k_bscan(const int* __restrict__ bcnt, int* __restrict__ bbase,
                        int* __restrict__ gcur, int nb, int total) {
    __shared__ int s[512];
    int tid = threadIdx.x;
    int v = (tid < nb) ? bcnt[tid] : 0;
    s[tid] = v;
    __syncthreads();
    for (int o = 1; o < 512; o <<= 1) {
        int t = (tid >= o) ? s[tid - o] : 0;
        __syncthreads();
        s[tid] += t;
        __syncthreads();
    }
    if (tid < nb) { int ex = s[tid] - v; bbase[tid] = ex; gcur[tid] = ex; }
    if (tid == 0) bbase[nb] = total;
}

// ---- partition packed records (local_key<<17 | other) into bucket regions ----
// per-block LDS histogram + one chunk-reservation atomic per (block,bucket):
// writes are contiguous ~84B runs per bucket -> dense, L2-friendly
__global__ void k_part(const int* __restrict__ key, const int* __restrict__ oth,
                       int* __restrict__ gcur, unsigned int* __restrict__ rec,
                       int nb, int ne) {
    __shared__ int cnt[NBU];    // max(NBI,NBU)
    __shared__ int gbase[NBU];
    int tid = threadIdx.x;
    for (int b = tid; b < nb; b += 256) cnt[b] = 0;
    __syncthreads();
    int base = blockIdx.x * CHUNK;
    int myk[16]; int myb[16]; unsigned int myr[16];
#pragma unroll
    for (int k = 0; k < 16; k++) {
        int j = base + tid + k * 256;
        myb[k] = -1;
        if (j < ne) {
            int d = key[j];
            int b = d >> 8;
            myb[k] = b;
            myr[k] = ((unsigned int)(d & 255) << 17) | (unsigned int)oth[j];
            myk[k] = atomicAdd(&cnt[b], 1);
        }
    }
    __syncthreads();
    for (int b = tid; b < nb; b += 256) {
        int c = cnt[b];
        if (c) gbase[b] = atomicAdd(&gcur[b], c);
    }
    __syncthreads();
#pragma unroll
    for (int k = 0; k < 16; k++) {
        if (myb[k] >= 0) rec[gbase[myb[k]] + myk[k]] = myr[k];
    }
}

// ---- per-bucket local fill: exclusive ownership, LDS counters/scan ----
// produces rp (per-node row pointers, replaces k_degrees + global scan) and col;
// col writes land in a ~20KB block-exclusive dense region -> no line waste
__global__ void k_local(const unsigned int* __restrict__ rec, const int* __restrict__ bbase,
                        int* __restrict__ rp, int* __restrict__ col, int n_nodes) {
    __shared__ int cnt[256];
    __shared__ int off[256];
    int tid = threadIdx.x;
    int b = blockIdx.x;
    int beg = bbase[b], end = bbase[b + 1];
    cnt[tid] = 0;
    __syncthreads();
    for (int j = beg + tid; j < end; j += 256)
        atomicAdd(&cnt[rec[j] >> 17], 1);
    __syncthreads();
    int v = cnt[tid];
    off[tid] = v;
    __syncthreads();
    for (int o = 1; o < 256; o <<= 1) {
        int t = (tid >= o) ? off[tid - o] : 0;
        __syncthreads();
        off[tid] += t;
        __syncthreads();
    }
    int ex = off[tid] - v;   // exclusive scan
    int node = b * 256 + tid;
    if (node <= n_nodes) rp[node] = beg + ex;   // node==n_nodes lands on NE naturally
    cnt[tid] = ex;           // reuse as cursor
    __syncthreads();
    for (int j = beg + tid; j < end; j += 256) {
        unsigned int r = rec[j];
        int ln = r >> 17;
        int p = atomicAdd(&cnt[ln], 1);
        col[beg + p] = (int)(r & 0x1FFFF);
    }
}

// ---- pull aggregation + fused finalize: one wave per dst node, lane = dim ----
__global__ void k_agg(const float* __restrict__ feat, const float* self,
                      const float* __restrict__ sw, const int* __restrict__ rp,
                      const int* __restrict__ cols, float* out, int n_dst) {
    int gtid = blockIdx.x * blockDim.x + threadIdx.x;
    int w = gtid >> 6;
    int lane = threadIdx.x & 63;
    if (w >= n_dst) return;
    int beg = rp[w], end = rp[w + 1];
    float a0 = 0.f, a1 = 0.f, a2 = 0.f, a3 = 0.f;
    int j = beg;
    for (; j + 4 <= end; j += 4) {
        int c0 = cols[j], c1 = cols[j + 1], c2 = cols[j + 2], c3 = cols[j + 3];
        a0 += feat[c0 * D + lane];
        a1 += feat[c1 * D + lane];
        a2 += feat[c2 * D + lane];
        a3 += feat[c3 * D + lane];
    }
    for (; j < end; ++j) a0 += feat[cols[j] * D + lane];
    float acc = (a0 + a1) + (a2 + a3);
    int dgr = end - beg;
    float inv = (dgr > 0) ? (1.0f / (float)dgr) : 0.0f;
    out[w * D + lane] = acc * inv + self[w * D + lane] * sw[w];
}

extern "C" void kernel_launch(void* const* d_in, const int* in_sizes, int n_in,
                              void* d_out, int out_size, void* d_ws, size_t ws_size,
                              hipStream_t stream) {
    const float* user_emb = (const float*)d_in[0];
    const float* item_emb = (const float*)d_in[1];
    const float* u_sw     = (const float*)d_in[2];
    const float* i_sw     = (const float*)d_in[3];
    const int*   esrc     = (const int*)d_in[4];   // user endpoint
    const int*   edst     = (const int*)d_in[5];   // item endpoint

    float* out_u = (float*)d_out;
    float* out_i = out_u + NU * D;

    // workspace layout (~29.4 MB)
    int* bcnt    = (int*)d_ws;             // NB_TOT (item first, then user)
    int* bbase_i = bcnt + NB_TOT;          // NBI+1
    int* bbase_u = bbase_i + NBI + 1;      // NBU+1
    int* gcur_i  = bbase_u + NBU + 1;      // NBI
    int* gcur_u  = gcur_i + NBI;           // NBU
    unsigned int* rec_i = (unsigned int*)(gcur_u + NBU);  // NE
    unsigned int* rec_u = rec_i + NE;                     // NE
    int* rp_i = (int*)(rec_u + NE);        // NI+1
    int* rp_u = rp_i + NI + 1;             // NU+1
    int* col_i = rp_u + NU + 1;            // NE
    int* col_u = col_i + NE;               // NE
    float* tmp_i = (float*)(col_u + NE);   // NI*64

    hipMemsetAsync(bcnt, 0, NB_TOT * sizeof(int), stream);

    // ---- CSR build, bucketed ----
    k_bhist<<<512, 256, 0, stream>>>(esrc, edst, bcnt, NE);
    k_bscan<<<1, 512, 0, stream>>>(bcnt, bbase_i, gcur_i, NBI, NE);
    k_bscan<<<1, 512, 0, stream>>>(bcnt + NBI, bbase_u, gcur_u, NBU, NE);
    int pgrid = (NE + CHUNK - 1) / CHUNK;  // 245
    k_part<<<pgrid, 256, 0, stream>>>(edst, esrc, gcur_i, rec_i, NBI, NE);
    k_part<<<pgrid, 256, 0, stream>>>(esrc, edst, gcur_u, rec_u, NBU, NE);
    k_local<<<NBI, 256, 0, stream>>>(rec_i, bbase_i, rp_i, col_i, NI);
    k_local<<<NBU, 256, 0, stream>>>(rec_u, bbase_u, rp_u, col_u, NU);

    // ---- aggregation rounds (unchanged) ----
    int gi = (NI + 3) / 4;
    int gu = (NU + 3) / 4;
    const int B = 256;

    // round 1
    k_agg<<<gi, B, 0, stream>>>(user_emb, item_emb, i_sw, rp_i, col_i, tmp_i, NI);
    k_agg<<<gu, B, 0, stream>>>(item_emb, user_emb, u_sw, rp_u, col_u, out_u, NU);
    // round 2
    k_agg<<<gi, B, 0, stream>>>(out_u, tmp_i, i_sw, rp_i, col_i, out_i, NI);
    k_agg<<<gu, B, 0, stream>>>(tmp_i, out_u, u_sw, rp_u, col_u, out_u, NU);
}